// Round 17
// baseline (264.735 us; speedup 1.0000x reference)
//
#include <hip/hip_runtime.h>
#include <stdint.h>

typedef __bf16 bf16;
typedef __bf16 bf16x4 __attribute__((ext_vector_type(4)));
typedef __bf16 bf16x8 __attribute__((ext_vector_type(8)));
typedef float  f32x4  __attribute__((ext_vector_type(4)));
typedef float  f32x16 __attribute__((ext_vector_type(16)));

#define MFMA16(A, B, C) __builtin_amdgcn_mfma_f32_16x16x32_bf16((A), (B), (C), 0, 0, 0)
#define MFMA32(A, B, C) __builtin_amdgcn_mfma_f32_32x32x16_bf16((A), (B), (C), 0, 0, 0)

#define LOG2E 1.4426950408889634f

// B=960 windows, N=144, DIM=192, HEADS=6, hd=32, TYPES=64, n_mask=15
// Softmax: no-max exp2 (logits |L|<~6), log2e prefolded; P unnormalized, O scaled by 1/rsum.
// R8: k_attn min-waves stays 3. R10: bias/mask swizzled -> coalesced (worked).
// R11: store-coalescing NEUTRAL. R12/R13: stationary-W infeasible (allocator remats).
// R14: fragment-order W -> 106->95us (worked). R15/R16: reordering load bursts flat ->
//      k_qkv bound by LOAD-INSTRUCTION COUNT per FLOP.
// R17: 32x32x16 MFMA: same operand bytes/instr, 2x FLOP -> 2.9x fewer load instrs
//      per FLOP in k_qkv (24 W + 36 LDS per 2.36 MFLOP/wave); W read once per block.
//      Same shape for k_out. A/B loaded with matching lane maps (i=lane&31,
//      k=(lane>>5)*8+j); C/D: col=lane&31, row=(reg&3)+8(reg>>2)+4(lane>>5) [HW-verified].
//
// ws layout (bytes):
//   wqkvt [18][12][64][8] bf16 @ 0       (221184)  (fragment-order, 32x32 tiles)
//   woutt [6][12][64][8] bf16 @ 221184   (73728)   ends 294912 (fragment-order)
//   bias_sw [384][20736] bf16 @ 294912   (15925248) ends 16220160
//   obuf  [138240][192] bf16 @ 16220160  (53084160) ends 69304320
//   qb    [960][6][144][32] bf16 @ 69304320  ends 122388480
//   kb    same @ 122388480 ends 175472640
//   vtb   [960][6][32][144] @ 175472640 ends 228556800
//   mask_sw [15][20736] f32 @ 228556800  (1244160) ends 229800960 (~219.2 MiB)

// ---------------- weight transpose + bf16 cast (fragment-order for 32x32) ----------------
// o = ((ctile*12 + ks)*64 + lane)*8 + j  <->  W[k = ks*16 + (lane>>5)*8 + j][col = ctile*32 + (lane&31)]
__global__ __launch_bounds__(256) void k_prep(const float* __restrict__ wqkv,
                                              const float* __restrict__ wout,
                                              bf16* __restrict__ wqkvt,
                                              bf16* __restrict__ woutt) {
    int i = blockIdx.x * 256 + threadIdx.x;   // 576 blocks
    if (i < 576 * 192) {
        int blk = i >> 9;                     // ctile*12 + ks  (0..215)
        int within = i & 511;
        int lane = within >> 3, j = within & 7;
        int ct = blk / 12, ks = blk - ct * 12;
        int col = ct * 32 + (lane & 31);
        int k = ks * 16 + (lane >> 5) * 8 + j;
        wqkvt[i] = (bf16)wqkv[k * 576 + col];
    } else {
        int jj = i - 576 * 192;               // 0..36863
        int blk = jj >> 9;                    // ctile*12 + ks  (0..71)
        int within = jj & 511;
        int lane = within >> 3, j = within & 7;
        int ct = blk / 12, ks = blk - ct * 12;
        int col = ct * 32 + (lane & 31);
        int k = ks * 16 + (lane >> 5) * 8 + j;
        woutt[jj] = (bf16)wout[k * 192 + col];
    }
}

// ---------------- earth-bias materialization (swizzled, pre-mult log2e) ----------------
__global__ __launch_bounds__(256) void k_bias(const float* __restrict__ btab,
                                              bf16* __restrict__ bias) {
    __shared__ float tb[3312];
    const int th = blockIdx.x;                 // t*6 + h
    for (int i = threadIdx.x; i < 3312; i += 256)
        tb[i] = btab[(size_t)i * 384 + th] * LOG2E;
    __syncthreads();
    bf16* op = bias + (size_t)th * 20736;
    for (int o = threadIdx.x; o < 20736; o += 256) {
        int nt = o / 2304, r1 = o - nt * 2304;
        int ct = r1 / 256,  r2 = r1 - ct * 256;
        int l15 = r2 >> 4,  gr = r2 & 15;
        int n = nt * 16 + l15, m = ct * 16 + gr;
        int zn = n / 72, rn = n - zn * 72, hn = rn / 12, wn = rn - hn * 12;
        int zm = m / 72, rm = m - zm * 72, hm = rm / 12, wm = rm - hm * 12;
        int idx = 828 * (zn + 2 * zm) + 23 * (hn + 6 * hm) + (wn - wm + 11);
        op[o] = (bf16)tb[idx];
    }
}

// ---------------- mask swizzle ----------------
__global__ __launch_bounds__(256) void k_mswz(const float* __restrict__ mask,
                                              float* __restrict__ msw) {
    const int wm = blockIdx.x / 9;
    const int nt = blockIdx.x - wm * 9;
    const int tid = threadIdx.x;
    const int l15 = tid >> 4, gr = tid & 15;
    const float* src = mask + (size_t)wm * 20736 + (size_t)(nt * 16 + l15) * 144 + gr;
    float* dst = msw + (size_t)wm * 20736 + nt * 2304 + tid;
    #pragma unroll
    for (int ct = 0; ct < 9; ++ct)
        dst[ct * 256] = src[ct * 16];
}

// ---------------- QKV projection: 32x32 MFMA, 9 waves x 64 cols ----------------
// grid 1440 (96 rows), 576 thr = 9 waves; wave w owns col-tiles 2w, 2w+1 (64 cols).
// Per wave: 12 ksteps x (2 W loads + 3 LDS reads) + 72 MFMA32; W read once per block.
__global__ __launch_bounds__(576, 2) void k_qkv(const float* __restrict__ x,
                                                const float* __restrict__ bqkv,
                                                const bf16* __restrict__ wtf,
                                                bf16* __restrict__ qb,
                                                bf16* __restrict__ kb,
                                                bf16* __restrict__ vtb) {
    __shared__ bf16 xs[96][200];               // 38400 B
    const int tid = threadIdx.x;
    const int lane = tid & 63;
    const int w = tid >> 6;                    // 0..8
    const int l31 = lane & 31;
    const int hi = lane >> 5;
    const int cg = w / 3;                      // 0=q 1=k 2=v (wave-uniform)
    const int cwave = w * 64;
    const int rowbase = blockIdx.x * 96;
    const float scl = (cg == 0) ? 0.17677669529663687f * LOG2E : 1.0f;

    // stage x tile: 96*192 f32 = 4608 f32x4 = 576 thr x 8 (coalesced, convert once)
    #pragma unroll
    for (int it = 0; it < 8; ++it) {
        int idx = tid + it * 576;
        int r = idx / 48, cp = idx - r * 48;
        f32x4 xa = *reinterpret_cast<const f32x4*>(x + (size_t)(rowbase + r) * 192 + cp * 4);
        bf16x4 v;
        v[0] = (bf16)xa[0]; v[1] = (bf16)xa[1]; v[2] = (bf16)xa[2]; v[3] = (bf16)xa[3];
        *reinterpret_cast<bf16x4*>(&xs[r][cp * 4]) = v;
    }
    __syncthreads();

    f32x16 a00{}, a01{}, a10{}, a11{}, a20{}, a21{};   // [row-tile][col-tile]
    const size_t wbase0 = (size_t)((w * 2 + 0) * 12) * 512 + lane * 8;
    const size_t wbase1 = (size_t)((w * 2 + 1) * 12) * 512 + lane * 8;
    #pragma unroll
    for (int ks = 0; ks < 12; ++ks) {
        bf16x8 aw0 = *reinterpret_cast<const bf16x8*>(wtf + wbase0 + ks * 512);
        bf16x8 aw1 = *reinterpret_cast<const bf16x8*>(wtf + wbase1 + ks * 512);
        bf16x8 b0 = *reinterpret_cast<const bf16x8*>(&xs[0  + l31][ks * 16 + hi * 8]);
        bf16x8 b1 = *reinterpret_cast<const bf16x8*>(&xs[32 + l31][ks * 16 + hi * 8]);
        bf16x8 b2 = *reinterpret_cast<const bf16x8*>(&xs[64 + l31][ks * 16 + hi * 8]);
        a00 = MFMA32(aw0, b0, a00);  a01 = MFMA32(aw1, b0, a01);
        a10 = MFMA32(aw0, b1, a10);  a11 = MFMA32(aw1, b1, a11);
        a20 = MFMA32(aw0, b2, a20);  a21 = MFMA32(aw1, b2, a21);
    }

    // epilogue: D col(l31) = row n, row i = rg*8 + hi*4 + e = output col offset
    const int rem = cwave - cg * 192;          // col within group, 32-aligned
    bf16* qkbase = (cg == 0) ? qb : kb;
    #pragma unroll
    for (int rt = 0; rt < 3; ++rt) {
        const unsigned ng = rowbase + rt * 32 + l31;
        const int bidx = ng / 144;
        const int n = ng - bidx * 144;
        #pragma unroll
        for (int ct2 = 0; ct2 < 2; ++ct2) {
            const f32x16 av = (rt == 0) ? (ct2 ? a01 : a00)
                            : (rt == 1) ? (ct2 ? a11 : a10)
                                        : (ct2 ? a21 : a20);
            const int h = (rem + ct2 * 32) >> 5;           // wave-uniform head
            #pragma unroll
            for (int rg = 0; rg < 4; ++rg) {
                const int d0 = rg * 8 + hi * 4;
                f32x4 bvv = *reinterpret_cast<const f32x4*>(bqkv + cwave + ct2 * 32 + d0);
                float v0 = (av[rg * 4 + 0] + bvv[0]) * scl;
                float v1 = (av[rg * 4 + 1] + bvv[1]) * scl;
                float v2 = (av[rg * 4 + 2] + bvv[2]) * scl;
                float v3 = (av[rg * 4 + 3] + bvv[3]) * scl;
                if (cg == 2) {
                    bf16* dst = vtb + ((size_t)(bidx * 6 + h) * 32 + d0) * 144 + n;
                    dst[0]       = (bf16)v0;
                    dst[144]     = (bf16)v1;
                    dst[288]     = (bf16)v2;
                    dst[432]     = (bf16)v3;
                } else {
                    bf16x4 sv;
                    sv[0] = (bf16)v0; sv[1] = (bf16)v1; sv[2] = (bf16)v2; sv[3] = (bf16)v3;
                    *reinterpret_cast<bf16x4*>(qkbase + ((size_t)(bidx * 6 + h) * 144 + n) * 32 + d0) = sv;
                }
            }
        }
    }
}

// ---------------- windowed attention (R10/R14 form, unchanged) ----------------
__global__ __launch_bounds__(192, 3) void k_attn(const bf16* __restrict__ qb,
                                                 const bf16* __restrict__ kb,
                                                 const bf16* __restrict__ vtb,
                                                 const float* __restrict__ msw,
                                                 const bf16* __restrict__ bias,
                                                 bf16* __restrict__ ob) {
    __shared__ bf16 pl[48][168];
    const int hb = blockIdx.x;
    const int b = hb / 6;
    const int h = hb - b * 6;
    const int t = b & 63;
    const int wm = b % 15;
    const int tid = threadIdx.x;
    const int lane = tid & 63;
    const int wv = tid >> 6;
    const int l15 = lane & 15;
    const int g = lane >> 4;

    const bf16* qp = qb + (size_t)hb * 4608;
    const bf16* kp = kb + (size_t)hb * 4608;
    const bf16* vp = vtb + (size_t)hb * 4608;

    bf16x8 kf[9];
    #pragma unroll
    for (int ct = 0; ct < 9; ++ct)
        kf[ct] = *reinterpret_cast<const bf16x8*>(kp + (size_t)(ct * 16 + l15) * 32 + g * 8);
    bf16x8 vf[10];
    #pragma unroll
    for (int mc = 0; mc < 5; ++mc) {
        vf[mc]     = *reinterpret_cast<const bf16x8*>(vp + (size_t)l15 * 144 + mc * 32 + g * 8);
        vf[5 + mc] = *reinterpret_cast<const bf16x8*>(vp + (size_t)(16 + l15) * 144 + mc * 32 + g * 8);
    }

    if (lane < 32) {
        bf16x8 z;
        #pragma unroll
        for (int i = 0; i < 8; ++i) z[i] = (bf16)0.f;
        *reinterpret_cast<bf16x8*>(&pl[wv * 16 + (lane >> 1)][144 + (lane & 1) * 8]) = z;
    }

    const float* mbase = msw + (size_t)wm * 20736 + l15 * 16 + g * 4;
    const bf16* bbase = bias + (size_t)(t * 6 + h) * 20736 + l15 * 16 + g * 4;

    for (int j = 0; j < 3; ++j) {
        const int n = j * 48 + wv * 16 + l15;
        const int nt = j * 3 + wv;

        bf16x8 bq = *reinterpret_cast<const bf16x8*>(qp + (size_t)n * 32 + g * 8);
        f32x4 s[9];
        #pragma unroll
        for (int ct = 0; ct < 9; ++ct) {
            f32x4 z = (f32x4){0.f, 0.f, 0.f, 0.f};
            s[ct] = MFMA16(kf[ct], bq, z);
        }

        const bf16* brow = bbase + nt * 2304;
        const float* mrow = mbase + nt * 2304;
        #pragma unroll
        for (int ct = 0; ct < 9; ++ct) {
            bf16x4 bvv = *reinterpret_cast<const bf16x4*>(brow + ct * 256);
            f32x4 mv = *reinterpret_cast<const f32x4*>(mrow + ct * 256);
            #pragma unroll
            for (int r = 0; r < 4; ++r)
                s[ct][r] = exp2f(fmaf(mv[r], LOG2E, s[ct][r] + (float)bvv[r]));
        }

        f32x4 sm4 = s[8];
        #pragma unroll
        for (int ct = 0; ct < 4; ++ct) {
            #pragma unroll
            for (int r = 0; r < 4; ++r)
                sm4[r] += s[ct][r] + s[ct + 4][r];
        }
        float rsum = (sm4[0] + sm4[1]) + (sm4[2] + sm4[3]);
        rsum += __shfl_xor(rsum, 16);
        rsum += __shfl_xor(rsum, 32);
        const float rinv = 1.0f / rsum;

        #pragma unroll
        for (int ct = 0; ct < 9; ++ct) {
            bf16x4 pv;
            #pragma unroll
            for (int r = 0; r < 4; ++r) pv[r] = (bf16)s[ct][r];
            *reinterpret_cast<bf16x4*>(&pl[wv * 16 + l15][ct * 16 + g * 4]) = pv;
        }
        __asm__ __volatile__("s_waitcnt lgkmcnt(0)" ::: "memory");

        f32x4 o0 = (f32x4){0.f, 0.f, 0.f, 0.f};
        f32x4 o1 = (f32x4){0.f, 0.f, 0.f, 0.f};
        #pragma unroll
        for (int mc = 0; mc < 5; ++mc) {
            bf16x8 pa = *reinterpret_cast<const bf16x8*>(&pl[wv * 16 + l15][mc * 32 + g * 8]);
            o0 = MFMA16(vf[mc], pa, o0);
            o1 = MFMA16(vf[5 + mc], pa, o1);
        }
        bf16* op = ob + (size_t)b * 27648 + (size_t)n * 192 + h * 32;
        bf16x4 s0, s1;
        #pragma unroll
        for (int r = 0; r < 4; ++r) { s0[r] = (bf16)(o0[r] * rinv); s1[r] = (bf16)(o1[r] * rinv); }
        *reinterpret_cast<bf16x4*>(op + g * 4)      = s0;
        *reinterpret_cast<bf16x4*>(op + 16 + g * 4) = s1;
    }
}

// ---------------- output projection: 32x32 MFMA, 6 waves x 32 cols ----------------
// grid 1440 (96 rows), 384 thr = 6 waves; wave w owns col-tile w (32 cols).
__global__ __launch_bounds__(384, 2) void k_out(const bf16* __restrict__ ob,
                                                const bf16* __restrict__ wtf,
                                                const float* __restrict__ bout,
                                                float* __restrict__ out) {
    __shared__ bf16 os[96][200];               // 38400 B
    const int tid = threadIdx.x;
    const int lane = tid & 63;
    const int w = tid >> 6;                    // 0..5
    const int l31 = lane & 31;
    const int hi = lane >> 5;
    const int cbase = w * 32;
    const int rowbase = blockIdx.x * 96;

    // stage tile: 96*192 bf16 = 2304 bf16x8 = 384 thr x 6
    #pragma unroll
    for (int it = 0; it < 6; ++it) {
        int idx = tid + it * 384;
        int r = idx / 24, cp = idx - r * 24;
        bf16x8 v = *reinterpret_cast<const bf16x8*>(ob + (size_t)(rowbase + r) * 192 + cp * 8);
        *reinterpret_cast<bf16x8*>(&os[r][cp * 8]) = v;
    }
    __syncthreads();

    f32x16 a0{}, a1{}, a2{};
    const size_t wbase = (size_t)(w * 12) * 512 + lane * 8;
    #pragma unroll
    for (int ks = 0; ks < 12; ++ks) {
        bf16x8 aw = *reinterpret_cast<const bf16x8*>(wtf + wbase + ks * 512);
        bf16x8 b0 = *reinterpret_cast<const bf16x8*>(&os[0  + l31][ks * 16 + hi * 8]);
        bf16x8 b1 = *reinterpret_cast<const bf16x8*>(&os[32 + l31][ks * 16 + hi * 8]);
        bf16x8 b2 = *reinterpret_cast<const bf16x8*>(&os[64 + l31][ks * 16 + hi * 8]);
        a0 = MFMA32(aw, b0, a0);
        a1 = MFMA32(aw, b1, a1);
        a2 = MFMA32(aw, b2, a2);
    }

    #pragma unroll
    for (int rt = 0; rt < 3; ++rt) {
        const f32x16 av = (rt == 0) ? a0 : (rt == 1) ? a1 : a2;
        const int n = rowbase + rt * 32 + l31;
        #pragma unroll
        for (int rg = 0; rg < 4; ++rg) {
            const int c4 = cbase + rg * 8 + hi * 4;
            f32x4 bvv = *reinterpret_cast<const f32x4*>(bout + c4);
            f32x4 v;
            v[0] = av[rg * 4 + 0] + bvv[0];
            v[1] = av[rg * 4 + 1] + bvv[1];
            v[2] = av[rg * 4 + 2] + bvv[2];
            v[3] = av[rg * 4 + 3] + bvv[3];
            *reinterpret_cast<f32x4*>(out + (size_t)n * 192 + c4) = v;
        }
    }
}

extern "C" void kernel_launch(void* const* d_in, const int* in_sizes, int n_in,
                              void* d_out, int out_size, void* d_ws, size_t ws_size,
                              hipStream_t stream) {
    const float* x    = (const float*)d_in[0];
    const float* mask = (const float*)d_in[1];
    const float* wqkv = (const float*)d_in[2];
    const float* bqkv = (const float*)d_in[3];
    const float* wout = (const float*)d_in[4];
    const float* bout = (const float*)d_in[5];
    const float* btab = (const float*)d_in[6];
    float* out = (float*)d_out;

    char* ws = (char*)d_ws;
    bf16* wqkvt = (bf16*)(ws);
    bf16* woutt = (bf16*)(ws + 221184);
    bf16* bias  = (bf16*)(ws + 294912);
    bf16* obuf  = (bf16*)(ws + 16220160);
    bf16* qb    = (bf16*)(ws + 69304320);
    bf16* kb    = (bf16*)(ws + 122388480);
    bf16* vtb   = (bf16*)(ws + 175472640);  // ends 228556800
    float* msw  = (float*)(ws + 228556800); // ends 229800960 (~219.2 MiB)

    hipLaunchKernelGGL(k_prep, dim3(576),  dim3(256), 0, stream, wqkv, wout, wqkvt, woutt);
    hipLaunchKernelGGL(k_bias, dim3(384),  dim3(256), 0, stream, btab, bias);
    hipLaunchKernelGGL(k_mswz, dim3(135),  dim3(256), 0, stream, mask, msw);
    hipLaunchKernelGGL(k_qkv,  dim3(1440), dim3(576), 0, stream, x, bqkv, wqkvt, qb, kb, vtb);
    hipLaunchKernelGGL(k_attn, dim3(5760), dim3(192), 0, stream, qb, kb, vtb, msw, bias, obuf);
    hipLaunchKernelGGL(k_out,  dim3(1440), dim3(384), 0, stream, obuf, woutt, bout, out);
}

// Round 18
// 247.931 us; speedup vs baseline: 1.0678x; 1.0678x over previous
//
#include <hip/hip_runtime.h>
#include <stdint.h>

typedef __bf16 bf16;
typedef __bf16 bf16x4 __attribute__((ext_vector_type(4)));
typedef __bf16 bf16x8 __attribute__((ext_vector_type(8)));
typedef float  f32x4  __attribute__((ext_vector_type(4)));

#define MFMA16(A, B, C) __builtin_amdgcn_mfma_f32_16x16x32_bf16((A), (B), (C), 0, 0, 0)

#define LOG2E 1.4426950408889634f

// B=960 windows, N=144, DIM=192, HEADS=6, hd=32, TYPES=64, n_mask=15
// Softmax: no-max exp2 (logits |L|<~6), log2e prefolded; P unnormalized, O scaled by 1/rsum.
// R8: k_attn launch_bounds must leave ~170 VGPR budget (min-waves 3).
// R10: bias/mask swizzled -> coalesced (worked). R11: store-coalescing NEUTRAL.
// R12/R13: stationary-W infeasible (allocator remats). R14: fragment-order W -> 95us (BEST).
// R15/R16/R17: k_qkv variations all flat-or-worse -> R14 k_qkv/k_out retained.
// R18: k_attn 1 wave/block x 9 q-tiles (was 3x3): K/V frag loads 3x fewer,
//      reuse x9, LDS 5.4KB, 5760 independent single-wave blocks.
//
// ws layout (bytes):
//   wqkvt [36][6][64][8] bf16 @ 0        (221184)  (fragment-order, 16x16 strips)
//   woutt [192][192] bf16 @ 221184       (73728)   ends 294912 ([n][k] k-contig)
//   bias_sw [384][20736] bf16 @ 294912   (15925248) ends 16220160
//   obuf  [138240][192] bf16 @ 16220160  (53084160) ends 69304320
//   qb    [960][6][144][32] bf16 @ 69304320  ends 122388480
//   kb    same @ 122388480 ends 175472640
//   vtb   [960][6][32][144] @ 175472640 ends 228556800
//   mask_sw [15][20736] f32 @ 228556800  (1244160) ends 229800960 (~219.2 MiB)

// ---------------- weight transpose + bf16 cast ----------------
// wqkvt fragment-order: o = ((strip*6 + ks)*64 + lane)*8 + j
//   <-> W[k = ks*32 + (lane>>4)*8 + j][col = strip*16 + (lane&15)]
__global__ __launch_bounds__(256) void k_prep(const float* __restrict__ wqkv,
                                              const float* __restrict__ wout,
                                              bf16* __restrict__ wqkvt,
                                              bf16* __restrict__ woutt) {
    int i = blockIdx.x * 256 + threadIdx.x;   // 576 blocks
    if (i < 576 * 192) {
        int blk = i >> 9;                     // strip*6 + ks  (0..215)
        int within = i & 511;
        int lane = within >> 3, j = within & 7;
        int strip = blk / 6, ks = blk - strip * 6;
        int col = strip * 16 + (lane & 15);
        int k = ks * 32 + (lane >> 4) * 8 + j;
        wqkvt[i] = (bf16)wqkv[k * 576 + col];
    } else {
        int jj = i - 576 * 192;
        int n = jj / 192, k = jj - n * 192;
        woutt[jj] = (bf16)wout[k * 192 + n];  // [n][k], k-contiguous
    }
}

// ---------------- earth-bias materialization (swizzled, pre-mult log2e) ----------------
__global__ __launch_bounds__(256) void k_bias(const float* __restrict__ btab,
                                              bf16* __restrict__ bias) {
    __shared__ float tb[3312];
    const int th = blockIdx.x;                 // t*6 + h
    for (int i = threadIdx.x; i < 3312; i += 256)
        tb[i] = btab[(size_t)i * 384 + th] * LOG2E;
    __syncthreads();
    bf16* op = bias + (size_t)th * 20736;
    for (int o = threadIdx.x; o < 20736; o += 256) {
        int nt = o / 2304, r1 = o - nt * 2304;
        int ct = r1 / 256,  r2 = r1 - ct * 256;
        int l15 = r2 >> 4,  gr = r2 & 15;
        int n = nt * 16 + l15, m = ct * 16 + gr;
        int zn = n / 72, rn = n - zn * 72, hn = rn / 12, wn = rn - hn * 12;
        int zm = m / 72, rm = m - zm * 72, hm = rm / 12, wm = rm - hm * 12;
        int idx = 828 * (zn + 2 * zm) + 23 * (hn + 6 * hm) + (wn - wm + 11);
        op[o] = (bf16)tb[idx];
    }
}

// ---------------- mask swizzle ----------------
__global__ __launch_bounds__(256) void k_mswz(const float* __restrict__ mask,
                                              float* __restrict__ msw) {
    const int wm = blockIdx.x / 9;
    const int nt = blockIdx.x - wm * 9;
    const int tid = threadIdx.x;
    const int l15 = tid >> 4, gr = tid & 15;
    const float* src = mask + (size_t)wm * 20736 + (size_t)(nt * 16 + l15) * 144 + gr;
    float* dst = msw + (size_t)wm * 20736 + nt * 2304 + tid;
    #pragma unroll
    for (int ct = 0; ct < 9; ++ct)
        dst[ct * 256] = src[ct * 16];
}

// ---------------- QKV projection (R14 exact: fragment-order W, per-subtile bursts) ----------------
// grid 1440 (96 rows), 768 thr = 12 waves; wave w owns strips 3w..3w+2 (48 cols).
__global__ __launch_bounds__(768, 3) void k_qkv(const float* __restrict__ x,
                                                const float* __restrict__ bqkv,
                                                const bf16* __restrict__ wtf,
                                                bf16* __restrict__ qb,
                                                bf16* __restrict__ kb,
                                                bf16* __restrict__ vtb) {
    __shared__ bf16 xs[96][200];               // 38400 B
    const int tid = threadIdx.x;
    const int lane = tid & 63;
    const int w = tid >> 6;
    const int l15 = lane & 15;
    const int g = lane >> 4;
    const int c0 = w * 48;
    const int rowbase = blockIdx.x * 96;

    // per-strip metadata
    int hs[3], d0s[3], cgs[3];
    float scl[3];
    f32x4 bv[3];
    #pragma unroll
    for (int s = 0; s < 3; ++s) {
        int cbase = c0 + s * 16;               // never crosses a 192 boundary
        int cg = cbase / 192;
        int rem = cbase - cg * 192;
        cgs[s] = cg;
        scl[s] = (cg == 0) ? 0.17677669529663687f * LOG2E : 1.0f;  // q pre-scaled for exp2
        hs[s] = rem >> 5;
        d0s[s] = (rem & 31) + g * 4;
        bv[s] = *reinterpret_cast<const f32x4*>(bqkv + cbase + g * 4);
    }

    // stage x tile: 96*192 f32 = 4608 f32x4 = 768 thr x 6 (coalesced, convert once)
    #pragma unroll
    for (int it = 0; it < 6; ++it) {
        int idx = tid + it * 768;
        int r = idx / 48, cp = idx - r * 48;
        f32x4 xa = *reinterpret_cast<const f32x4*>(x + (size_t)(rowbase + r) * 192 + cp * 4);
        bf16x4 v;
        v[0] = (bf16)xa[0]; v[1] = (bf16)xa[1]; v[2] = (bf16)xa[2]; v[3] = (bf16)xa[3];
        *reinterpret_cast<bf16x4*>(&xs[r][cp * 4]) = v;
    }
    __syncthreads();

    for (int sub = 0; sub < 6; ++sub) {
        const int row0 = rowbase + sub * 16;   // 16-aligned -> never crosses 144 boundary
        bf16x8 bfr[6];
        #pragma unroll
        for (int ks = 0; ks < 6; ++ks)
            bfr[ks] = *reinterpret_cast<const bf16x8*>(&xs[sub * 16 + l15][ks * 32 + g * 8]);
        f32x4 acc[3];
        #pragma unroll
        for (int s = 0; s < 3; ++s) acc[s] = (f32x4){0.f, 0.f, 0.f, 0.f};
        #pragma unroll
        for (int ks = 0; ks < 6; ++ks) {
            #pragma unroll
            for (int s = 0; s < 3; ++s) {
                bf16x8 aw = *reinterpret_cast<const bf16x8*>(wtf + (size_t)(((w * 3 + s) * 6 + ks) * 512 + lane * 8));
                acc[s] = MFMA16(aw, bfr[ks], acc[s]);
            }
        }
        // D: row(g*4+r) = output col, col(l15) = x-row
        const int bidx = row0 / 144;
        const int n = row0 - bidx * 144 + l15;
        #pragma unroll
        for (int s = 0; s < 3; ++s) {
            float v0 = (acc[s][0] + bv[s][0]) * scl[s];
            float v1 = (acc[s][1] + bv[s][1]) * scl[s];
            float v2 = (acc[s][2] + bv[s][2]) * scl[s];
            float v3 = (acc[s][3] + bv[s][3]) * scl[s];
            if (cgs[s] == 2) {
                bf16* dst = vtb + ((size_t)(bidx * 6 + hs[s]) * 32 + d0s[s]) * 144 + n;
                dst[0]   = (bf16)v0;
                dst[144] = (bf16)v1;
                dst[288] = (bf16)v2;
                dst[432] = (bf16)v3;
            } else {
                bf16x4 sv;
                sv[0] = (bf16)v0; sv[1] = (bf16)v1; sv[2] = (bf16)v2; sv[3] = (bf16)v3;
                bf16* base = (cgs[s] == 0) ? qb : kb;
                *reinterpret_cast<bf16x4*>(base + ((size_t)(bidx * 6 + hs[s]) * 144 + n) * 32 + d0s[s]) = sv;
            }
        }
    }
}

// ---------------- windowed attention: 1 wave/block, 9 q-tiles, K/V register-resident ----------------
// grid 5760 = (b,h); 64 thr = 1 wave. K (9) + V (10) frags loaded once, reused across 9 tiles.
__global__ __launch_bounds__(64, 3) void k_attn(const bf16* __restrict__ qb,
                                                const bf16* __restrict__ kb,
                                                const bf16* __restrict__ vtb,
                                                const float* __restrict__ msw,
                                                const bf16* __restrict__ bias,
                                                bf16* __restrict__ ob) {
    __shared__ bf16 pl[16][168];   // one wave's P rows; m padded 144->160 zeros
    const int hb = blockIdx.x;
    const int b = hb / 6;
    const int h = hb - b * 6;
    const int t = b & 63;
    const int wm = b % 15;
    const int lane = threadIdx.x & 63;
    const int l15 = lane & 15;
    const int g = lane >> 4;

    const bf16* qp = qb + (size_t)hb * 4608;
    const bf16* kp = kb + (size_t)hb * 4608;
    const bf16* vp = vtb + (size_t)hb * 4608;

    // K and V fragments: load once per block (76 VGPR)
    bf16x8 kf[9];
    #pragma unroll
    for (int ct = 0; ct < 9; ++ct)
        kf[ct] = *reinterpret_cast<const bf16x8*>(kp + (size_t)(ct * 16 + l15) * 32 + g * 8);
    bf16x8 vf[10];
    #pragma unroll
    for (int mc = 0; mc < 5; ++mc) {
        vf[mc]     = *reinterpret_cast<const bf16x8*>(vp + (size_t)l15 * 144 + mc * 32 + g * 8);
        vf[5 + mc] = *reinterpret_cast<const bf16x8*>(vp + (size_t)(16 + l15) * 144 + mc * 32 + g * 8);
    }

    // zero the m-pad cols [144,160) of the 16 P rows
    if (lane < 32) {
        bf16x8 z;
        #pragma unroll
        for (int i = 0; i < 8; ++i) z[i] = (bf16)0.f;
        *reinterpret_cast<bf16x8*>(&pl[lane >> 1][144 + (lane & 1) * 8]) = z;
    }

    const float* mbase = msw + (size_t)wm * 20736 + l15 * 16 + g * 4;
    const bf16* bbase = bias + (size_t)(t * 6 + h) * 20736 + l15 * 16 + g * 4;

    for (int j = 0; j < 9; ++j) {
        const int n = j * 16 + l15;            // this thread's softmax row

        // ---- S^T = K·Q^T : D row(g*4+r)=m, col(l15)=n ----
        bf16x8 bq = *reinterpret_cast<const bf16x8*>(qp + (size_t)n * 32 + g * 8);
        f32x4 s[9];
        #pragma unroll
        for (int ct = 0; ct < 9; ++ct) {
            f32x4 z = (f32x4){0.f, 0.f, 0.f, 0.f};
            s[ct] = MFMA16(kf[ct], bq, z);
        }

        // ---- + bias' + mask*log2e (swizzled, coalesced), p = exp2(.) ----
        const bf16* brow = bbase + j * 2304;
        const float* mrow = mbase + j * 2304;
        #pragma unroll
        for (int ct = 0; ct < 9; ++ct) {
            bf16x4 bvv = *reinterpret_cast<const bf16x4*>(brow + ct * 256);
            f32x4 mv = *reinterpret_cast<const f32x4*>(mrow + ct * 256);
            #pragma unroll
            for (int r = 0; r < 4; ++r)
                s[ct][r] = exp2f(fmaf(mv[r], LOG2E, s[ct][r] + (float)bvv[r]));
        }

        // ---- tree sum (row denominator) ----
        f32x4 sm4 = s[8];
        #pragma unroll
        for (int ct = 0; ct < 4; ++ct) {
            #pragma unroll
            for (int r = 0; r < 4; ++r)
                sm4[r] += s[ct][r] + s[ct + 4][r];
        }
        float rsum = (sm4[0] + sm4[1]) + (sm4[2] + sm4[3]);
        rsum += __shfl_xor(rsum, 16);
        rsum += __shfl_xor(rsum, 32);
        const float rinv = 1.0f / rsum;

        // unnormalized P -> LDS (reused each tile)
        #pragma unroll
        for (int ct = 0; ct < 9; ++ct) {
            bf16x4 pv;
            #pragma unroll
            for (int r = 0; r < 4; ++r) pv[r] = (bf16)s[ct][r];
            *reinterpret_cast<bf16x4*>(&pl[l15][ct * 16 + g * 4]) = pv;
        }
        __asm__ __volatile__("s_waitcnt lgkmcnt(0)" ::: "memory");  // same-wave write->read

        // ---- O^T = V·P^T : D row(g*4+r)=d, col(l15)=n ----
        f32x4 o0 = (f32x4){0.f, 0.f, 0.f, 0.f};
        f32x4 o1 = (f32x4){0.f, 0.f, 0.f, 0.f};
        #pragma unroll
        for (int mc = 0; mc < 5; ++mc) {
            bf16x8 pa = *reinterpret_cast<const bf16x8*>(&pl[l15][mc * 32 + g * 8]);
            o0 = MFMA16(vf[mc], pa, o0);
            o1 = MFMA16(vf[5 + mc], pa, o1);
        }
        // thread holds O[n][d = g*4+r (+16 for o1)], scaled by rinv -> 2 vector stores
        bf16* op = ob + (size_t)b * 27648 + (size_t)n * 192 + h * 32;
        bf16x4 s0, s1;
        #pragma unroll
        for (int r = 0; r < 4; ++r) { s0[r] = (bf16)(o0[r] * rinv); s1[r] = (bf16)(o1[r] * rinv); }
        *reinterpret_cast<bf16x4*>(op + g * 4)      = s0;
        *reinterpret_cast<bf16x4*>(op + 16 + g * 4) = s1;
    }
}

// ---------------- output projection (R14 form, unchanged) ----------------
__global__ __launch_bounds__(768, 3) void k_out(const bf16* __restrict__ ob,
                                                const bf16* __restrict__ wt,
                                                const float* __restrict__ bout,
                                                float* __restrict__ out) {
    __shared__ bf16 os[96][200];
    __shared__ float ot[16][196];
    const int tid = threadIdx.x;
    const int lane = tid & 63;
    const int w = tid >> 6;
    const int l15 = lane & 15;
    const int g = lane >> 4;
    const int c0 = w * 16;
    const int rowbase = blockIdx.x * 96;

    bf16x8 a[6];
    #pragma unroll
    for (int ks = 0; ks < 6; ++ks)
        a[ks] = *reinterpret_cast<const bf16x8*>(wt + (size_t)(c0 + l15) * 192 + ks * 32 + g * 8);
    f32x4 bv = *reinterpret_cast<const f32x4*>(bout + c0 + g * 4);

    #pragma unroll
    for (int it = 0; it < 3; ++it) {
        int idx = tid + it * 768;
        int r = idx / 24, cp = idx - r * 24;
        bf16x8 v = *reinterpret_cast<const bf16x8*>(ob + (size_t)(rowbase + r) * 192 + cp * 8);
        *reinterpret_cast<bf16x8*>(&os[r][cp * 8]) = v;
    }
    __syncthreads();

    for (int sub = 0; sub < 6; ++sub) {
        bf16x8 bfr[6];
        #pragma unroll
        for (int ks = 0; ks < 6; ++ks)
            bfr[ks] = *reinterpret_cast<const bf16x8*>(&os[sub * 16 + l15][ks * 32 + g * 8]);
        f32x4 acc = (f32x4){0.f, 0.f, 0.f, 0.f};
        #pragma unroll
        for (int ks = 0; ks < 6; ++ks)
            acc = MFMA16(a[ks], bfr[ks], acc);
        __syncthreads();
        f32x4 sv;
        sv[0] = acc[0] + bv[0];
        sv[1] = acc[1] + bv[1];
        sv[2] = acc[2] + bv[2];
        sv[3] = acc[3] + bv[3];
        *reinterpret_cast<f32x4*>(&ot[l15][c0 + g * 4]) = sv;
        __syncthreads();
        int rr = tid / 48, c4 = tid - rr * 48;
        f32x4 vv = *reinterpret_cast<const f32x4*>(&ot[rr][c4 * 4]);
        *reinterpret_cast<f32x4*>(out + (size_t)(rowbase + sub * 16 + rr) * 192 + c4 * 4) = vv;
    }
}

extern "C" void kernel_launch(void* const* d_in, const int* in_sizes, int n_in,
                              void* d_out, int out_size, void* d_ws, size_t ws_size,
                              hipStream_t stream) {
    const float* x    = (const float*)d_in[0];
    const float* mask = (const float*)d_in[1];
    const float* wqkv = (const float*)d_in[2];
    const float* bqkv = (const float*)d_in[3];
    const float* wout = (const float*)d_in[4];
    const float* bout = (const float*)d_in[5];
    const float* btab = (const float*)d_in[6];
    float* out = (float*)d_out;

    char* ws = (char*)d_ws;
    bf16* wqkvt = (bf16*)(ws);
    bf16* woutt = (bf16*)(ws + 221184);
    bf16* bias  = (bf16*)(ws + 294912);
    bf16* obuf  = (bf16*)(ws + 16220160);
    bf16* qb    = (bf16*)(ws + 69304320);
    bf16* kb    = (bf16*)(ws + 122388480);
    bf16* vtb   = (bf16*)(ws + 175472640);  // ends 228556800
    float* msw  = (float*)(ws + 228556800); // ends 229800960 (~219.2 MiB)

    hipLaunchKernelGGL(k_prep, dim3(576),  dim3(256), 0, stream, wqkv, wout, wqkvt, woutt);
    hipLaunchKernelGGL(k_bias, dim3(384),  dim3(256), 0, stream, btab, bias);
    hipLaunchKernelGGL(k_mswz, dim3(135),  dim3(256), 0, stream, mask, msw);
    hipLaunchKernelGGL(k_qkv,  dim3(1440), dim3(768), 0, stream, x, bqkv, wqkvt, qb, kb, vtb);
    hipLaunchKernelGGL(k_attn, dim3(5760), dim3(64),  0, stream, qb, kb, vtb, msw, bias, obuf);
    hipLaunchKernelGGL(k_out,  dim3(1440), dim3(768), 0, stream, obuf, woutt, bout, out);
}

// Round 20
// 230.145 us; speedup vs baseline: 1.1503x; 1.0773x over previous
//
#include <hip/hip_runtime.h>
#include <stdint.h>

typedef __bf16 bf16;
typedef __bf16 bf16x4 __attribute__((ext_vector_type(4)));
typedef __bf16 bf16x8 __attribute__((ext_vector_type(8)));
typedef float  f32x4  __attribute__((ext_vector_type(4)));

#define MFMA16(A, B, C) __builtin_amdgcn_mfma_f32_16x16x32_bf16((A), (B), (C), 0, 0, 0)

#define LOG2E 1.4426950408889634f

// B=960 windows, N=144, DIM=192, HEADS=6, hd=32, TYPES=64, n_mask=15
// Softmax: no-max exp2 (logits |L|<~6), log2e prefolded; P unnormalized, O scaled by 1/rsum.
// R8: k_attn launch_bounds keeps >=170 VGPR budget. R10: bias/mask swizzled (worked).
// R11: store-coalescing NEUTRAL. R12/R13: stationary-W infeasible. R14: fragment-order W (BEST 234.9).
// R15-R17: k_qkv variants flat/worse. R18: 1-wave attn cut FETCH but lost occupancy.
// R19 lesson (NaN): PV reads V-operand m up to 159; V pad must be ZEROED LDS, not
//      uninitialized (NaN x 0 = NaN through MFMA). R20 = R19 + vsh padded to 160 and
//      pad cols [144,160) explicitly zero-filled before the barrier.
//
// ws layout (bytes):
//   wqkvt [36][6][64][8] bf16 @ 0        (221184)  (fragment-order, 16x16 strips)
//   woutt [192][192] bf16 @ 221184       (73728)   ends 294912 ([n][k] k-contig)
//   bias_sw [384][20736] bf16 @ 294912   (15925248) ends 16220160
//   obuf  [138240][192] bf16 @ 16220160  (53084160) ends 69304320
//   qb    [960][6][144][32] bf16 @ 69304320  ends 122388480
//   kb    same @ 122388480 ends 175472640
//   vtb   [960][6][32][144] @ 175472640 ends 228556800
//   mask_sw [15][20736] f32 @ 228556800  (1244160) ends 229800960 (~219.2 MiB)

// ---------------- weight transpose + bf16 cast ----------------
__global__ __launch_bounds__(256) void k_prep(const float* __restrict__ wqkv,
                                              const float* __restrict__ wout,
                                              bf16* __restrict__ wqkvt,
                                              bf16* __restrict__ woutt) {
    int i = blockIdx.x * 256 + threadIdx.x;   // 576 blocks
    if (i < 576 * 192) {
        int blk = i >> 9;                     // strip*6 + ks  (0..215)
        int within = i & 511;
        int lane = within >> 3, j = within & 7;
        int strip = blk / 6, ks = blk - strip * 6;
        int col = strip * 16 + (lane & 15);
        int k = ks * 32 + (lane >> 4) * 8 + j;
        wqkvt[i] = (bf16)wqkv[k * 576 + col];
    } else {
        int jj = i - 576 * 192;
        int n = jj / 192, k = jj - n * 192;
        woutt[jj] = (bf16)wout[k * 192 + n];  // [n][k], k-contiguous
    }
}

// ---------------- earth-bias materialization (swizzled, pre-mult log2e) ----------------
__global__ __launch_bounds__(256) void k_bias(const float* __restrict__ btab,
                                              bf16* __restrict__ bias) {
    __shared__ float tb[3312];
    const int th = blockIdx.x;                 // t*6 + h
    for (int i = threadIdx.x; i < 3312; i += 256)
        tb[i] = btab[(size_t)i * 384 + th] * LOG2E;
    __syncthreads();
    bf16* op = bias + (size_t)th * 20736;
    for (int o = threadIdx.x; o < 20736; o += 256) {
        int nt = o / 2304, r1 = o - nt * 2304;
        int ct = r1 / 256,  r2 = r1 - ct * 256;
        int l15 = r2 >> 4,  gr = r2 & 15;
        int n = nt * 16 + l15, m = ct * 16 + gr;
        int zn = n / 72, rn = n - zn * 72, hn = rn / 12, wn = rn - hn * 12;
        int zm = m / 72, rm = m - zm * 72, hm = rm / 12, wm = rm - hm * 12;
        int idx = 828 * (zn + 2 * zm) + 23 * (hn + 6 * hm) + (wn - wm + 11);
        op[o] = (bf16)tb[idx];
    }
}

// ---------------- mask swizzle ----------------
__global__ __launch_bounds__(256) void k_mswz(const float* __restrict__ mask,
                                              float* __restrict__ msw) {
    const int wm = blockIdx.x / 9;
    const int nt = blockIdx.x - wm * 9;
    const int tid = threadIdx.x;
    const int l15 = tid >> 4, gr = tid & 15;
    const float* src = mask + (size_t)wm * 20736 + (size_t)(nt * 16 + l15) * 144 + gr;
    float* dst = msw + (size_t)wm * 20736 + nt * 2304 + tid;
    #pragma unroll
    for (int ct = 0; ct < 9; ++ct)
        dst[ct * 256] = src[ct * 16];
}

// ---------------- QKV projection (R14 exact) ----------------
// grid 1440 (96 rows), 768 thr = 12 waves; wave w owns strips 3w..3w+2 (48 cols).
__global__ __launch_bounds__(768, 3) void k_qkv(const float* __restrict__ x,
                                                const float* __restrict__ bqkv,
                                                const bf16* __restrict__ wtf,
                                                bf16* __restrict__ qb,
                                                bf16* __restrict__ kb,
                                                bf16* __restrict__ vtb) {
    __shared__ bf16 xs[96][200];               // 38400 B
    const int tid = threadIdx.x;
    const int lane = tid & 63;
    const int w = tid >> 6;
    const int l15 = lane & 15;
    const int g = lane >> 4;
    const int c0 = w * 48;
    const int rowbase = blockIdx.x * 96;

    int hs[3], d0s[3], cgs[3];
    float scl[3];
    f32x4 bv[3];
    #pragma unroll
    for (int s = 0; s < 3; ++s) {
        int cbase = c0 + s * 16;
        int cg = cbase / 192;
        int rem = cbase - cg * 192;
        cgs[s] = cg;
        scl[s] = (cg == 0) ? 0.17677669529663687f * LOG2E : 1.0f;
        hs[s] = rem >> 5;
        d0s[s] = (rem & 31) + g * 4;
        bv[s] = *reinterpret_cast<const f32x4*>(bqkv + cbase + g * 4);
    }

    #pragma unroll
    for (int it = 0; it < 6; ++it) {
        int idx = tid + it * 768;
        int r = idx / 48, cp = idx - r * 48;
        f32x4 xa = *reinterpret_cast<const f32x4*>(x + (size_t)(rowbase + r) * 192 + cp * 4);
        bf16x4 v;
        v[0] = (bf16)xa[0]; v[1] = (bf16)xa[1]; v[2] = (bf16)xa[2]; v[3] = (bf16)xa[3];
        *reinterpret_cast<bf16x4*>(&xs[r][cp * 4]) = v;
    }
    __syncthreads();

    for (int sub = 0; sub < 6; ++sub) {
        const int row0 = rowbase + sub * 16;
        bf16x8 bfr[6];
        #pragma unroll
        for (int ks = 0; ks < 6; ++ks)
            bfr[ks] = *reinterpret_cast<const bf16x8*>(&xs[sub * 16 + l15][ks * 32 + g * 8]);
        f32x4 acc[3];
        #pragma unroll
        for (int s = 0; s < 3; ++s) acc[s] = (f32x4){0.f, 0.f, 0.f, 0.f};
        #pragma unroll
        for (int ks = 0; ks < 6; ++ks) {
            #pragma unroll
            for (int s = 0; s < 3; ++s) {
                bf16x8 aw = *reinterpret_cast<const bf16x8*>(wtf + (size_t)(((w * 3 + s) * 6 + ks) * 512 + lane * 8));
                acc[s] = MFMA16(aw, bfr[ks], acc[s]);
            }
        }
        const int bidx = row0 / 144;
        const int n = row0 - bidx * 144 + l15;
        #pragma unroll
        for (int s = 0; s < 3; ++s) {
            float v0 = (acc[s][0] + bv[s][0]) * scl[s];
            float v1 = (acc[s][1] + bv[s][1]) * scl[s];
            float v2 = (acc[s][2] + bv[s][2]) * scl[s];
            float v3 = (acc[s][3] + bv[s][3]) * scl[s];
            if (cgs[s] == 2) {
                bf16* dst = vtb + ((size_t)(bidx * 6 + hs[s]) * 32 + d0s[s]) * 144 + n;
                dst[0]   = (bf16)v0;
                dst[144] = (bf16)v1;
                dst[288] = (bf16)v2;
                dst[432] = (bf16)v3;
            } else {
                bf16x4 sv;
                sv[0] = (bf16)v0; sv[1] = (bf16)v1; sv[2] = (bf16)v2; sv[3] = (bf16)v3;
                bf16* base = (cgs[s] == 0) ? qb : kb;
                *reinterpret_cast<bf16x4*>(base + ((size_t)(bidx * 6 + hs[s]) * 144 + n) * 32 + d0s[s]) = sv;
            }
        }
    }
}

// ---------------- windowed attention: 3 waves, K/V staged once via LDS (zeroed V pad) ----------------
// grid 5760 = (b,h); 192 thr = 3 waves; wave wv handles q-tiles {j*48 + wv*16}.
__global__ __launch_bounds__(192, 3) void k_attn(const bf16* __restrict__ qb,
                                                 const bf16* __restrict__ kb,
                                                 const bf16* __restrict__ vtb,
                                                 const float* __restrict__ msw,
                                                 const bf16* __restrict__ bias,
                                                 bf16* __restrict__ ob) {
    __shared__ bf16 ksh[144][40];   // K rows padded 32->40
    __shared__ bf16 vsh[32][160];   // V^T rows padded 144->160; cols [144,160) ZEROED
    __shared__ bf16 pl[48][168];    // P rows; m padded 144->160 zeros
    const int hb = blockIdx.x;
    const int b = hb / 6;
    const int h = hb - b * 6;
    const int t = b & 63;
    const int wm = b % 15;
    const int tid = threadIdx.x;
    const int lane = tid & 63;
    const int wv = tid >> 6;       // 0..2
    const int l15 = lane & 15;
    const int g = lane >> 4;

    const bf16* qp = qb + (size_t)hb * 4608;
    const bf16* kp = kb + (size_t)hb * 4608;
    const bf16* vp = vtb + (size_t)hb * 4608;

    // cooperative staging: K (144x32) and V^T (32x144), coalesced bf16x8
    #pragma unroll
    for (int it = 0; it < 3; ++it) {
        int c = tid + it * 192;                 // 0..575
        int kr = c >> 2, kc = (c & 3) * 8;
        bf16x8 kvv = *reinterpret_cast<const bf16x8*>(kp + (size_t)kr * 32 + kc);
        *reinterpret_cast<bf16x8*>(&ksh[kr][kc]) = kvv;
        int vr = c / 18, vc = (c - vr * 18) * 8;
        bf16x8 vvv = *reinterpret_cast<const bf16x8*>(vp + (size_t)vr * 144 + vc);
        *reinterpret_cast<bf16x8*>(&vsh[vr][vc]) = vvv;
    }
    {
        bf16x8 z;
        #pragma unroll
        for (int i = 0; i < 8; ++i) z[i] = (bf16)0.f;
        if (tid < 64)   // zero V pad cols [144,160): 32 rows x 2 chunks
            *reinterpret_cast<bf16x8*>(&vsh[tid >> 1][144 + (tid & 1) * 8]) = z;
        if (lane < 32)  // zero this wave's P pad cols [144,160)
            *reinterpret_cast<bf16x8*>(&pl[wv * 16 + (lane >> 1)][144 + (lane & 1) * 8]) = z;
    }
    __syncthreads();

    // register fragments from LDS (once per wave, reused across 3 q-tiles)
    bf16x8 kf[9];
    #pragma unroll
    for (int ct = 0; ct < 9; ++ct)
        kf[ct] = *reinterpret_cast<const bf16x8*>(&ksh[ct * 16 + l15][g * 8]);
    bf16x8 vf[10];
    #pragma unroll
    for (int mc = 0; mc < 5; ++mc) {
        vf[mc]     = *reinterpret_cast<const bf16x8*>(&vsh[l15][mc * 32 + g * 8]);
        vf[5 + mc] = *reinterpret_cast<const bf16x8*>(&vsh[16 + l15][mc * 32 + g * 8]);
    }

    const float* mbase = msw + (size_t)wm * 20736 + l15 * 16 + g * 4;
    const bf16* bbase = bias + (size_t)(t * 6 + h) * 20736 + l15 * 16 + g * 4;

    for (int j = 0; j < 3; ++j) {
        const int n = j * 48 + wv * 16 + l15;
        const int nt = j * 3 + wv;

        // ---- S^T = K·Q^T ----
        bf16x8 bq = *reinterpret_cast<const bf16x8*>(qp + (size_t)n * 32 + g * 8);
        f32x4 s[9];
        #pragma unroll
        for (int ct = 0; ct < 9; ++ct) {
            f32x4 z = (f32x4){0.f, 0.f, 0.f, 0.f};
            s[ct] = MFMA16(kf[ct], bq, z);
        }

        // ---- + bias' + mask*log2e (swizzled, coalesced), p = exp2(.) ----
        const bf16* brow = bbase + nt * 2304;
        const float* mrow = mbase + nt * 2304;
        #pragma unroll
        for (int ct = 0; ct < 9; ++ct) {
            bf16x4 bvv = *reinterpret_cast<const bf16x4*>(brow + ct * 256);
            f32x4 mv = *reinterpret_cast<const f32x4*>(mrow + ct * 256);
            #pragma unroll
            for (int r = 0; r < 4; ++r)
                s[ct][r] = exp2f(fmaf(mv[r], LOG2E, s[ct][r] + (float)bvv[r]));
        }

        // ---- tree sum ----
        f32x4 sm4 = s[8];
        #pragma unroll
        for (int ct = 0; ct < 4; ++ct) {
            #pragma unroll
            for (int r = 0; r < 4; ++r)
                sm4[r] += s[ct][r] + s[ct + 4][r];
        }
        float rsum = (sm4[0] + sm4[1]) + (sm4[2] + sm4[3]);
        rsum += __shfl_xor(rsum, 16);
        rsum += __shfl_xor(rsum, 32);
        const float rinv = 1.0f / rsum;

        // unnormalized P -> LDS (wave-local rows)
        #pragma unroll
        for (int ct = 0; ct < 9; ++ct) {
            bf16x4 pv;
            #pragma unroll
            for (int r = 0; r < 4; ++r) pv[r] = (bf16)s[ct][r];
            *reinterpret_cast<bf16x4*>(&pl[wv * 16 + l15][ct * 16 + g * 4]) = pv;
        }
        __asm__ __volatile__("s_waitcnt lgkmcnt(0)" ::: "memory");

        // ---- O^T = V·P^T ----
        f32x4 o0 = (f32x4){0.f, 0.f, 0.f, 0.f};
        f32x4 o1 = (f32x4){0.f, 0.f, 0.f, 0.f};
        #pragma unroll
        for (int mc = 0; mc < 5; ++mc) {
            bf16x8 pa = *reinterpret_cast<const bf16x8*>(&pl[wv * 16 + l15][mc * 32 + g * 8]);
            o0 = MFMA16(vf[mc], pa, o0);
            o1 = MFMA16(vf[5 + mc], pa, o1);
        }
        bf16* op = ob + (size_t)b * 27648 + (size_t)n * 192 + h * 32;
        bf16x4 s0, s1;
        #pragma unroll
        for (int r = 0; r < 4; ++r) { s0[r] = (bf16)(o0[r] * rinv); s1[r] = (bf16)(o1[r] * rinv); }
        *reinterpret_cast<bf16x4*>(op + g * 4)      = s0;
        *reinterpret_cast<bf16x4*>(op + 16 + g * 4) = s1;
    }
}

// ---------------- output projection (R14 form, unchanged) ----------------
__global__ __launch_bounds__(768, 3) void k_out(const bf16* __restrict__ ob,
                                                const bf16* __restrict__ wt,
                                                const float* __restrict__ bout,
                                                float* __restrict__ out) {
    __shared__ bf16 os[96][200];
    __shared__ float ot[16][196];
    const int tid = threadIdx.x;
    const int lane = tid & 63;
    const int w = tid >> 6;
    const int l15 = lane & 15;
    const int g = lane >> 4;
    const int c0 = w * 16;
    const int rowbase = blockIdx.x * 96;

    bf16x8 a[6];
    #pragma unroll
    for (int ks = 0; ks < 6; ++ks)
        a[ks] = *reinterpret_cast<const bf16x8*>(wt + (size_t)(c0 + l15) * 192 + ks * 32 + g * 8);
    f32x4 bv = *reinterpret_cast<const f32x4*>(bout + c0 + g * 4);

    #pragma unroll
    for (int it = 0; it < 3; ++it) {
        int idx = tid + it * 768;
        int r = idx / 24, cp = idx - r * 24;
        bf16x8 v = *reinterpret_cast<const bf16x8*>(ob + (size_t)(rowbase + r) * 192 + cp * 8);
        *reinterpret_cast<bf16x8*>(&os[r][cp * 8]) = v;
    }
    __syncthreads();

    for (int sub = 0; sub < 6; ++sub) {
        bf16x8 bfr[6];
        #pragma unroll
        for (int ks = 0; ks < 6; ++ks)
            bfr[ks] = *reinterpret_cast<const bf16x8*>(&os[sub * 16 + l15][ks * 32 + g * 8]);
        f32x4 acc = (f32x4){0.f, 0.f, 0.f, 0.f};
        #pragma unroll
        for (int ks = 0; ks < 6; ++ks)
            acc = MFMA16(a[ks], bfr[ks], acc);
        __syncthreads();
        f32x4 sv;
        sv[0] = acc[0] + bv[0];
        sv[1] = acc[1] + bv[1];
        sv[2] = acc[2] + bv[2];
        sv[3] = acc[3] + bv[3];
        *reinterpret_cast<f32x4*>(&ot[l15][c0 + g * 4]) = sv;
        __syncthreads();
        int rr = tid / 48, c4 = tid - rr * 48;
        f32x4 vv = *reinterpret_cast<const f32x4*>(&ot[rr][c4 * 4]);
        *reinterpret_cast<f32x4*>(out + (size_t)(rowbase + sub * 16 + rr) * 192 + c4 * 4) = vv;
    }
}

extern "C" void kernel_launch(void* const* d_in, const int* in_sizes, int n_in,
                              void* d_out, int out_size, void* d_ws, size_t ws_size,
                              hipStream_t stream) {
    const float* x    = (const float*)d_in[0];
    const float* mask = (const float*)d_in[1];
    const float* wqkv = (const float*)d_in[2];
    const float* bqkv = (const float*)d_in[3];
    const float* wout = (const float*)d_in[4];
    const float* bout = (const float*)d_in[5];
    const float* btab = (const float*)d_in[6];
    float* out = (float*)d_out;

    char* ws = (char*)d_ws;
    bf16* wqkvt = (bf16*)(ws);
    bf16* woutt = (bf16*)(ws + 221184);
    bf16* bias  = (bf16*)(ws + 294912);
    bf16* obuf  = (bf16*)(ws + 16220160);
    bf16* qb    = (bf16*)(ws + 69304320);
    bf16* kb    = (bf16*)(ws + 122388480);
    bf16* vtb   = (bf16*)(ws + 175472640);  // ends 228556800
    float* msw  = (float*)(ws + 228556800); // ends 229800960 (~219.2 MiB)

    hipLaunchKernelGGL(k_prep, dim3(576),  dim3(256), 0, stream, wqkv, wout, wqkvt, woutt);
    hipLaunchKernelGGL(k_bias, dim3(384),  dim3(256), 0, stream, btab, bias);
    hipLaunchKernelGGL(k_mswz, dim3(135),  dim3(256), 0, stream, mask, msw);
    hipLaunchKernelGGL(k_qkv,  dim3(1440), dim3(768), 0, stream, x, bqkv, wqkvt, qb, kb, vtb);
    hipLaunchKernelGGL(k_attn, dim3(5760), dim3(192), 0, stream, qb, kb, vtb, msw, bias, obuf);
    hipLaunchKernelGGL(k_out,  dim3(1440), dim3(768), 0, stream, obuf, woutt, bout, out);
}